// Round 6
// baseline (35.630 us; speedup 1.0000x reference)
//
#include <hip/hip_runtime.h>
#include <hip/hip_bf16.h>

#define NBATCH 512
#define NS 66
#define ND 304
#define NK 128

typedef __attribute__((ext_vector_type(8))) short bf16x8;
typedef __attribute__((ext_vector_type(4))) short s16x4;
typedef __attribute__((ext_vector_type(4))) float f32x4;

__device__ __forceinline__ short f2bf(float x) {
    return __builtin_bit_cast(short, __float2bfloat16(x));
}

// ======================= Kernel A: t = x . W^T (bf16) =======================
// grid = 1024 (2 blocks/batch: s-rows [0,48) and [48,66)), 512 threads.
#define A_THREADS 512
#define A_XSTRIDE 640                       // 320 bf16 per row
#define A_XROWS 48
#define A_XBYTES (A_XROWS * A_XSTRIDE)      // 30720

__global__ __launch_bounds__(A_THREADS, 4) void treeprobe_t(
    const float* __restrict__ x,   // [512][66][304]
    const float* __restrict__ W,   // [128][304]
    short* __restrict__ tg)        // [512][66][128] bf16
{
    __shared__ __align__(16) char lds[A_XBYTES];

    const int tid   = threadIdx.x;
    const int bid   = blockIdx.x;
    const int batch = bid >> 1;
    const int half  = bid & 1;
    const int lane  = tid & 63;
    const int wv    = tid >> 6;     // 0..7 : N-tile (16 t-cols)
    const int lr    = lane & 15;
    const int lg    = lane >> 4;

    const int r0     = half * 48;               // global s base (48 % 8 == 0)
    const int nreal  = half ? (NS - 48) : 48;   // 18 : 48 real rows
    const int ntiles = half ? 2 : 3;            // 16-row M-tiles
    const int nE     = nreal * 76;              // float4 elements to stage

    const float* __restrict__ xb = x + (size_t)batch * NS * ND + (size_t)r0 * ND;

    // ---- issue x loads ----
    float4 ax[8];
#pragma unroll
    for (int i = 0; i < 8; ++i) {
        const int e = tid + i * A_THREADS;
        ax[i] = (e < nE)
            ? *reinterpret_cast<const float4*>(xb + (e / 76) * ND + (e % 76) * 4)
            : make_float4(0.f, 0.f, 0.f, 0.f);
    }

    // ---- W fragments (A-operand): idx = lane&15 (t col), k = kk*32+lg*8+i ----
    bf16x8 wfrag[10];
    {
        const int c = wv * 16 + lr;
        const float* __restrict__ wr = W + c * ND;
#pragma unroll
        for (int kk = 0; kk < 10; ++kk) {
            const int k0 = kk * 32 + lg * 8;
            bf16x8 f = {0, 0, 0, 0, 0, 0, 0, 0};
            if (k0 < ND) {
                const float4 p0 = *reinterpret_cast<const float4*>(wr + k0);
                const float4 p1 = *reinterpret_cast<const float4*>(wr + k0 + 4);
                f[0] = f2bf(p0.x); f[1] = f2bf(p0.y);
                f[2] = f2bf(p0.z); f[3] = f2bf(p0.w);
                f[4] = f2bf(p1.x); f[5] = f2bf(p1.y);
                f[6] = f2bf(p1.z); f[7] = f2bf(p1.w);
            }
            wfrag[kk] = f;
        }
    }

    // ---- zero fills: k-pad cols [608,640)B of real rows; pad rows (half1) ----
    for (int i = tid; i < nreal * 2; i += A_THREADS) {
        const int ls = i >> 1;
        const int byte = (ls * A_XSTRIDE + 608 + (i & 1) * 16) ^ ((ls & 7) << 4);
        *reinterpret_cast<f32x4*>(lds + byte) = (f32x4){0.f, 0.f, 0.f, 0.f};
    }
    if (half) {     // local rows 18..31 (global 66..79): full-row zero
        for (int i = tid; i < 14 * 40; i += A_THREADS) {
            const int ls = 18 + i / 40;
            *reinterpret_cast<f32x4*>(lds + ls * A_XSTRIDE + (i % 40) * 16) =
                (f32x4){0.f, 0.f, 0.f, 0.f};
        }
    }

    // ---- convert + write x to LDS (swizzled by local row) ----
#pragma unroll
    for (int i = 0; i < 8; ++i) {
        const int e = tid + i * A_THREADS;
        if (e < nE) {
            const int ls  = e / 76;
            const int col = (e % 76) * 4;
            const int byte = (ls * A_XSTRIDE + col * 2) ^ ((ls & 7) << 4);
            s16x4 sv;
            sv[0] = f2bf(ax[i].x); sv[1] = f2bf(ax[i].y);
            sv[2] = f2bf(ax[i].z); sv[3] = f2bf(ax[i].w);
            *reinterpret_cast<s16x4*>(lds + byte) = sv;
        }
    }
    __syncthreads();

    // ---- MFMA: t-tile = W . x^T (swapped operands) ----
    f32x4 acc[3];
#pragma unroll
    for (int mt = 0; mt < 3; ++mt) acc[mt] = (f32x4){0.f, 0.f, 0.f, 0.f};

#pragma unroll
    for (int kk = 0; kk < 10; ++kk) {
        bf16x8 a[3];
#pragma unroll
        for (int mt = 0; mt < 3; ++mt) {
            if (mt < ntiles) {
                const int ls = mt * 16 + lr;
                const int byte = (ls * A_XSTRIDE + kk * 64 + lg * 16) ^ ((ls & 7) << 4);
                a[mt] = *reinterpret_cast<const bf16x8*>(lds + byte);
            }
        }
#pragma unroll
        for (int mt = 0; mt < 3; ++mt)
            if (mt < ntiles)
                acc[mt] = __builtin_amdgcn_mfma_f32_16x16x32_bf16(
                    wfrag[kk], a[mt], acc[mt], 0, 0, 0);
    }

    // ---- store t: D col(lane&15)=s-in-tile, row(lg*4+r)=t-col-in-tile ----
#pragma unroll
    for (int mt = 0; mt < 3; ++mt) {
        if (mt < ntiles) {
            const int s = r0 + mt * 16 + lr;
            if (s < NS) {
                s16x4 sv;
                sv[0] = f2bf(acc[mt][0]); sv[1] = f2bf(acc[mt][1]);
                sv[2] = f2bf(acc[mt][2]); sv[3] = f2bf(acc[mt][3]);
                *reinterpret_cast<s16x4*>(
                    tg + ((size_t)batch * NS + s) * NK + wv * 16 + lg * 4) = sv;
            }
        }
    }
}

// ============== Kernel B: G = t.t^T, out = nrm_i + nrm_j - 2G ==============
// grid = 1024 (2 blocks/batch; each does 5 diagonal + 5 strict-upper tiles).
#define B_THREADS 256
#define T_STRIDE_B 256
#define T_BYTES (80 * T_STRIDE_B)           // 20480

// per-half tile lists: positions 0-4 = diagonal (0,0)..(4,4); 5-9 strict-upper
__device__ const int BI_LUT[2][10] = {{0,1,2,3,4, 0,0,0,0,1},
                                      {0,1,2,3,4, 1,1,2,2,3}};
__device__ const int BJ_LUT[2][10] = {{0,1,2,3,4, 1,2,3,4,2},
                                      {0,1,2,3,4, 3,4,3,4,4}};

__global__ __launch_bounds__(B_THREADS, 4) void treeprobe_out(
    const short* __restrict__ tg,  // [512][66][128] bf16
    float* __restrict__ out)       // [512][66][66]
{
    __shared__ __align__(16) char t_lds[T_BYTES];
    __shared__ float norms[80];

    const int tid   = threadIdx.x;
    const int bid   = blockIdx.x;
    const int batch = bid >> 1;
    const int h     = bid & 1;
    const int lane  = tid & 63;
    const int wv    = tid >> 6;     // 0..3
    const int lr    = lane & 15;
    const int lg    = lane >> 4;

    // ---- zero pad rows 66..79 ----
    for (int i = tid; i < 14 * 16; i += B_THREADS) {
        const int s = 66 + i / 16;
        *reinterpret_cast<f32x4*>(t_lds + s * T_STRIDE_B + (i % 16) * 16) =
            (f32x4){0.f, 0.f, 0.f, 0.f};
    }
    // ---- stage t rows 0..65 into swizzled LDS (1056 16B chunks) ----
    const short* __restrict__ tb = tg + (size_t)batch * NS * NK;
#pragma unroll
    for (int i = 0; i < 5; ++i) {
        const int e = tid + i * B_THREADS;
        if (e < 1056) {
            const int s = e / 16;
            const int c = e % 16;
            const bf16x8 v = *reinterpret_cast<const bf16x8*>(tb + s * NK + c * 8);
            const int byte = (s * T_STRIDE_B + c * 16) ^ ((s & 7) << 4);
            *reinterpret_cast<bf16x8*>(t_lds + byte) = v;
        }
    }
    __syncthreads();

    // ---- G tiles in registers: wave slots {wv, wv+4, wv+8} of 10 ----
    f32x4 g[3];
    int ti[3], tj[3];
    bool valid[3], isdiag[3];
#pragma unroll
    for (int si = 0; si < 3; ++si) {
        const int pos = wv + si * 4;
        valid[si]  = pos < 10;
        g[si] = (f32x4){0.f, 0.f, 0.f, 0.f};
        ti[si] = 0; tj[si] = 0; isdiag[si] = false;
        if (valid[si]) {
            ti[si] = BI_LUT[h][pos];
            tj[si] = BJ_LUT[h][pos];
            isdiag[si] = pos < 5;
#pragma unroll
            for (int kk = 0; kk < 4; ++kk) {
                const int ra = ti[si] * 16 + lr;
                const int ba = (ra * T_STRIDE_B + kk * 64 + lg * 16) ^ ((ra & 7) << 4);
                const int rb = tj[si] * 16 + lr;
                const int bb = (rb * T_STRIDE_B + kk * 64 + lg * 16) ^ ((rb & 7) << 4);
                g[si] = __builtin_amdgcn_mfma_f32_16x16x32_bf16(
                    *reinterpret_cast<const bf16x8*>(t_lds + ba),
                    *reinterpret_cast<const bf16x8*>(t_lds + bb), g[si], 0, 0, 0);
            }
            if (isdiag[si]) {
#pragma unroll
                for (int r = 0; r < 4; ++r)
                    if (lr == lg * 4 + r) norms[ti[si] * 16 + lr] = g[si][r];
            }
        }
    }
    __syncthreads();

    // ---- epilogue ----
    float* __restrict__ ob = out + (size_t)batch * NS * NS;
#pragma unroll
    for (int si = 0; si < 3; ++si) {
        if (valid[si]) {
            const int j = tj[si] * 16 + lr;
            const float nj = norms[j];
            float v[4];
#pragma unroll
            for (int r = 0; r < 4; ++r) {
                const int i_ = ti[si] * 16 + lg * 4 + r;
                v[r] = norms[i_] + nj - 2.f * g[si][r];
                // diagonal tiles written only by h==0 (avoid duplicate writes)
                if (i_ < NS && j < NS && (h == 0 || !isdiag[si]))
                    ob[i_ * NS + j] = v[r];
            }
            if (!isdiag[si] && j < NS) {        // mirror (ti<=3 -> i0+3 <= 63)
                const int i0 = ti[si] * 16 + lg * 4;
                *reinterpret_cast<float2*>(ob + j * NS + i0)     = make_float2(v[0], v[1]);
                *reinterpret_cast<float2*>(ob + j * NS + i0 + 2) = make_float2(v[2], v[3]);
            }
        }
    }
}

// ===================== fused fallback (R4 structure) =====================
#define F_THREADS 512
#define F_XSTRIDE 640
#define F_XBYTES (80 * F_XSTRIDE)
#define F_TBYTES (80 * 256)

__device__ const int TI_LUT[15] = {0,1,2,3,4, 0,0,0,0,1,1,1,2,2,3};
__device__ const int TJ_LUT[15] = {0,1,2,3,4, 1,2,3,4,2,3,4,3,4,4};

__global__ __launch_bounds__(F_THREADS, 4) void treeprobe_fused(
    const float* __restrict__ x, const float* __restrict__ W,
    float* __restrict__ out)
{
    __shared__ __align__(16) char lds[F_XBYTES + F_TBYTES + 80 * 4];
    char* const t_lds = lds + F_XBYTES;
    float* const norms = (float*)(lds + F_XBYTES + F_TBYTES);

    const int tid = threadIdx.x, batch = blockIdx.x;
    const int lane = tid & 63, wv = tid >> 6, lr = lane & 15, lg = lane >> 4;
    const float* __restrict__ xb = x + (size_t)batch * NS * ND;

    float4 aA[6], aB[5];
#pragma unroll
    for (int i = 0; i < 6; ++i) {
        const int e = tid + i * F_THREADS;
        aA[i] = (e < 2640)
            ? *reinterpret_cast<const float4*>(xb + (e / 40) * ND + (e % 40) * 4)
            : make_float4(0.f, 0.f, 0.f, 0.f);
    }
#pragma unroll
    for (int i = 0; i < 5; ++i) {
        const int e = tid + i * F_THREADS;
        aB[i] = (e < 2376)
            ? *reinterpret_cast<const float4*>(xb + (e / 36) * ND + 160 + (e % 36) * 4)
            : make_float4(0.f, 0.f, 0.f, 0.f);
    }
    bf16x8 wfrag[10];
    {
        const int c = wv * 16 + lr;
        const float* __restrict__ wr = W + c * ND;
#pragma unroll
        for (int kk = 0; kk < 10; ++kk) {
            const int k0 = kk * 32 + lg * 8;
            bf16x8 f = {0, 0, 0, 0, 0, 0, 0, 0};
            if (k0 < ND) {
                const float4 p0 = *reinterpret_cast<const float4*>(wr + k0);
                const float4 p1 = *reinterpret_cast<const float4*>(wr + k0 + 4);
                f[0] = f2bf(p0.x); f[1] = f2bf(p0.y); f[2] = f2bf(p0.z); f[3] = f2bf(p0.w);
                f[4] = f2bf(p1.x); f[5] = f2bf(p1.y); f[6] = f2bf(p1.z); f[7] = f2bf(p1.w);
            }
            wfrag[kk] = f;
        }
    }
    for (int i = tid; i < 560; i += F_THREADS) {
        const int row = 66 + i / 40;
        *reinterpret_cast<f32x4*>(lds + row * F_XSTRIDE + (i % 40) * 16) =
            (f32x4){0.f, 0.f, 0.f, 0.f};
    }
    for (int i = tid; i < 132; i += F_THREADS) {
        const int row = i >> 1;
        const int byte = (row * F_XSTRIDE + 608 + (i & 1) * 16) ^ ((row & 7) << 4);
        *reinterpret_cast<f32x4*>(lds + byte) = (f32x4){0.f, 0.f, 0.f, 0.f};
    }
#pragma unroll
    for (int i = 0; i < 6; ++i) {
        const int e = tid + i * F_THREADS;
        if (e < 2640) {
            const int s = e / 40, f = (e % 40) * 4;
            const int byte = (s * F_XSTRIDE + f * 2) ^ ((s & 7) << 4);
            s16x4 sv;
            sv[0] = f2bf(aA[i].x); sv[1] = f2bf(aA[i].y);
            sv[2] = f2bf(aA[i].z); sv[3] = f2bf(aA[i].w);
            *reinterpret_cast<s16x4*>(lds + byte) = sv;
        }
    }
#pragma unroll
    for (int i = 0; i < 5; ++i) {
        const int e = tid + i * F_THREADS;
        if (e < 2376) {
            const int s = e / 36, f = 160 + (e % 36) * 4;
            const int byte = (s * F_XSTRIDE + f * 2) ^ ((s & 7) << 4);
            s16x4 sv;
            sv[0] = f2bf(aB[i].x); sv[1] = f2bf(aB[i].y);
            sv[2] = f2bf(aB[i].z); sv[3] = f2bf(aB[i].w);
            *reinterpret_cast<s16x4*>(lds + byte) = sv;
        }
    }
    __syncthreads();

    f32x4 acc[5];
#pragma unroll
    for (int st = 0; st < 5; ++st) acc[st] = (f32x4){0.f, 0.f, 0.f, 0.f};
#pragma unroll
    for (int kk = 0; kk < 10; ++kk) {
        bf16x8 a[5];
#pragma unroll
        for (int st = 0; st < 5; ++st) {
            const int row = st * 16 + lr;
            const int byte = (row * F_XSTRIDE + kk * 64 + lg * 16) ^ ((row & 7) << 4);
            a[st] = *reinterpret_cast<const bf16x8*>(lds + byte);
        }
#pragma unroll
        for (int st = 0; st < 5; ++st)
            acc[st] = __builtin_amdgcn_mfma_f32_16x16x32_bf16(
                wfrag[kk], a[st], acc[st], 0, 0, 0);
    }
#pragma unroll
    for (int st = 0; st < 5; ++st) {
        const int s = st * 16 + lr;
        const int c0 = wv * 16 + lg * 4;
        const int byte = (s * 256 + c0 * 2) ^ ((s & 7) << 4);
        s16x4 sv;
        sv[0] = f2bf(acc[st][0]); sv[1] = f2bf(acc[st][1]);
        sv[2] = f2bf(acc[st][2]); sv[3] = f2bf(acc[st][3]);
        *reinterpret_cast<s16x4*>(t_lds + byte) = sv;
    }
    __syncthreads();

    const int idx0 = wv, idx1 = wv + 8;
    const int ti0 = TI_LUT[idx0], tj0 = TJ_LUT[idx0];
    f32x4 g0 = (f32x4){0.f, 0.f, 0.f, 0.f};
#pragma unroll
    for (int kk = 0; kk < 4; ++kk) {
        const int ra = ti0 * 16 + lr;
        const int ba = (ra * 256 + kk * 64 + lg * 16) ^ ((ra & 7) << 4);
        const int rb = tj0 * 16 + lr;
        const int bb = (rb * 256 + kk * 64 + lg * 16) ^ ((rb & 7) << 4);
        g0 = __builtin_amdgcn_mfma_f32_16x16x32_bf16(
            *reinterpret_cast<const bf16x8*>(t_lds + ba),
            *reinterpret_cast<const bf16x8*>(t_lds + bb), g0, 0, 0, 0);
    }
    if (wv < 5) {
#pragma unroll
        for (int r = 0; r < 4; ++r)
            if (lr == lg * 4 + r) norms[wv * 16 + lr] = g0[r];
    }
    f32x4 g1 = (f32x4){0.f, 0.f, 0.f, 0.f};
    int ti1 = 0, tj1 = 0;
    if (idx1 < 15) {
        ti1 = TI_LUT[idx1]; tj1 = TJ_LUT[idx1];
#pragma unroll
        for (int kk = 0; kk < 4; ++kk) {
            const int ra = ti1 * 16 + lr;
            const int ba = (ra * 256 + kk * 64 + lg * 16) ^ ((ra & 7) << 4);
            const int rb = tj1 * 16 + lr;
            const int bb = (rb * 256 + kk * 64 + lg * 16) ^ ((rb & 7) << 4);
            g1 = __builtin_amdgcn_mfma_f32_16x16x32_bf16(
                *reinterpret_cast<const bf16x8*>(t_lds + ba),
                *reinterpret_cast<const bf16x8*>(t_lds + bb), g1, 0, 0, 0);
        }
    }
    __syncthreads();

    float* __restrict__ ob = out + (size_t)batch * NS * NS;
    {
        const int j = tj0 * 16 + lr;
        const float nj = norms[j];
        float v[4];
#pragma unroll
        for (int r = 0; r < 4; ++r) {
            const int i = ti0 * 16 + lg * 4 + r;
            v[r] = norms[i] + nj - 2.f * g0[r];
            if (i < NS && j < NS) ob[i * NS + j] = v[r];
        }
        if (ti0 != tj0 && j < NS) {
            const int i0 = ti0 * 16 + lg * 4;
            *reinterpret_cast<float2*>(ob + j * NS + i0)     = make_float2(v[0], v[1]);
            *reinterpret_cast<float2*>(ob + j * NS + i0 + 2) = make_float2(v[2], v[3]);
        }
    }
    if (idx1 < 15) {
        const int j = tj1 * 16 + lr;
        const float nj = norms[j];
        float v[4];
#pragma unroll
        for (int r = 0; r < 4; ++r) {
            const int i = ti1 * 16 + lg * 4 + r;
            v[r] = norms[i] + nj - 2.f * g1[r];
            if (i < NS && j < NS) ob[i * NS + j] = v[r];
        }
        if (j < NS) {
            const int i0 = ti1 * 16 + lg * 4;
            *reinterpret_cast<float2*>(ob + j * NS + i0)     = make_float2(v[0], v[1]);
            *reinterpret_cast<float2*>(ob + j * NS + i0 + 2) = make_float2(v[2], v[3]);
        }
    }
}

extern "C" void kernel_launch(void* const* d_in, const int* in_sizes, int n_in,
                              void* d_out, int out_size, void* d_ws, size_t ws_size,
                              hipStream_t stream) {
    const float* x = (const float*)d_in[0];   // (512, 66, 304) f32
    const float* W = (const float*)d_in[1];   // (128, 304) f32
    // d_in[2] = b : cancels in the pairwise difference, unused.
    float* out = (float*)d_out;               // (512, 66, 66) f32

    const size_t t_bytes = (size_t)NBATCH * NS * NK * 2;   // 8.65 MB bf16
    if (ws_size >= t_bytes) {
        short* tg = (short*)d_ws;
        treeprobe_t<<<NBATCH * 2, A_THREADS, 0, stream>>>(x, W, tg);
        treeprobe_out<<<NBATCH * 2, B_THREADS, 0, stream>>>(tg, out);
    } else {
        treeprobe_fused<<<NBATCH, F_THREADS, 0, stream>>>(x, W, out);
    }
}

// Round 7
// 25.630 us; speedup vs baseline: 1.3901x; 1.3901x over previous
//
#include <hip/hip_runtime.h>
#include <hip/hip_bf16.h>

#define NBATCH 512
#define NS 66
#define ND 304
#define NK 128
#define NTHREADS 512       // 8 waves

#define XSTRIDE_B 640      // 320 bf16 per row (K padded 304->320)
#define XBYTES (80 * XSTRIDE_B)             // 51200
#define TSTRIDE_B 256      // 128 bf16 per row
#define TBYTES (80 * TSTRIDE_B)             // 20480

typedef __attribute__((ext_vector_type(8))) short bf16x8;
typedef __attribute__((ext_vector_type(4))) short s16x4;
typedef __attribute__((ext_vector_type(4))) float f32x4;

__device__ __forceinline__ short f2bf(float x) {
    return __builtin_bit_cast(short, __float2bfloat16(x));
}

// 15 upper-triangle 16x16 tiles of G: 5 diagonal first, then 10 strict-upper.
__device__ const int TI_LUT[15] = {0,1,2,3,4, 0,0,0,0,1,1,1,2,2,3};
__device__ const int TJ_LUT[15] = {0,1,2,3,4, 1,2,3,4,2,3,4,3,4,4};

// raw barrier: LDS-writes visible, but outstanding global loads NOT drained
#define LDS_BARRIER() asm volatile("s_waitcnt lgkmcnt(0)\n\ts_barrier" ::: "memory")

__global__ __launch_bounds__(NTHREADS, 4) void treeprobe_mfma(
    const float* __restrict__ x,   // [512][66][304]
    const float* __restrict__ W,   // [128][304]
    float* __restrict__ out)       // [512][66][66]
{
    __shared__ __align__(16) char lds[XBYTES + TBYTES + 80 * 4];
    char* const t_lds = lds + XBYTES;
    float* const norms = (float*)(lds + XBYTES + TBYTES);

    const int tid   = threadIdx.x;
    const int batch = blockIdx.x;
    const int lane  = tid & 63;
    const int wv    = tid >> 6;     // wave 0..7 : N-tile (16 t-cols)
    const int lr    = lane & 15;
    const int lg    = lane >> 4;    // 0..3

    const float* __restrict__ xb = x + (size_t)batch * NS * ND;

    // x load-groups: e = g*512 + tid ; row = e/76 (rows ascend with g)
    // tile m (rows 16m..16m+15) needs groups < L(m), L = {3,5,8,10,10}
    float4 ax[10];

    // ---- issue x groups 0..2 (always in-bounds: e < 1536 < 5016) ----
#pragma unroll
    for (int g = 0; g < 3; ++g) {
        const int e = g * NTHREADS + tid;
        ax[g] = *reinterpret_cast<const float4*>(xb + (e / 76) * ND + (e % 76) * 4);
    }

    // ---- issue W loads (complete after groups 0-2, before groups 3-9) ----
    const int wc = wv * 16 + lr;                  // W row (t col) 0..127
    const float* __restrict__ wr = W + wc * ND;
    float4 wp[20];
#pragma unroll
    for (int kk = 0; kk < 10; ++kk) {
        const int k0 = kk * 32 + lg * 8;
        if (k0 < ND) {
            wp[kk * 2]     = *reinterpret_cast<const float4*>(wr + k0);
            wp[kk * 2 + 1] = *reinterpret_cast<const float4*>(wr + k0 + 4);
        } else {
            wp[kk * 2] = wp[kk * 2 + 1] = make_float4(0.f, 0.f, 0.f, 0.f);
        }
    }

    // ---- issue x groups 3..9 ----
#pragma unroll
    for (int g = 3; g < 10; ++g) {
        const int e = g * NTHREADS + tid;
        ax[g] = (e < 5016)
            ? *reinterpret_cast<const float4*>(xb + (e / 76) * ND + (e % 76) * 4)
            : make_float4(0.f, 0.f, 0.f, 0.f);
    }

    // ---- zero-fill pad regions (independent of loads) ----
    // rows 66..79 full width (whole rows: swizzle-invariant)
    for (int i = tid; i < 560; i += NTHREADS) {
        const int row = 66 + i / 40;
        *reinterpret_cast<f32x4*>(lds + row * XSTRIDE_B + (i % 40) * 16) =
            (f32x4){0.f, 0.f, 0.f, 0.f};
    }
    // k-pad cols [608,640)B of rows 0..65 (swizzled)
    for (int i = tid; i < 132; i += NTHREADS) {
        const int row = i >> 1;
        const int byte = (row * XSTRIDE_B + 608 + (i & 1) * 16) ^ ((row & 7) << 4);
        *reinterpret_cast<f32x4*>(lds + byte) = (f32x4){0.f, 0.f, 0.f, 0.f};
    }

    // ---- convert W -> A-operand fragments (waits W + groups 0-2 only) ----
    bf16x8 wfrag[10];
#pragma unroll
    for (int kk = 0; kk < 10; ++kk) {
        bf16x8 f;
        f[0] = f2bf(wp[kk * 2].x);     f[1] = f2bf(wp[kk * 2].y);
        f[2] = f2bf(wp[kk * 2].z);     f[3] = f2bf(wp[kk * 2].w);
        f[4] = f2bf(wp[kk * 2 + 1].x); f[5] = f2bf(wp[kk * 2 + 1].y);
        f[6] = f2bf(wp[kk * 2 + 1].z); f[7] = f2bf(wp[kk * 2 + 1].w);
        wfrag[kk] = f;
    }

    // ---- pipelined phase 1: per M-tile {convert new groups, barrier, MFMA} ----
    f32x4 acc[5];
#pragma unroll
    for (int st = 0; st < 5; ++st) acc[st] = (f32x4){0.f, 0.f, 0.f, 0.f};

    // groups converted+written before barrier m: [GS[m], GE[m])
    // (cumulative coverage = L(m) = {3,5,8,10,10})
#pragma unroll
    for (int m = 0; m < 5; ++m) {
        const int GS[5] = {0, 3, 5, 8, 10};
        const int GE[5] = {3, 5, 8, 10, 10};
#pragma unroll
        for (int g = 0; g < 10; ++g) {
            if (g >= GS[m] && g < GE[m]) {         // folds to static under unroll
                const int e = g * NTHREADS + tid;
                if (e < 5016) {
                    const int s = e / 76;
                    const int c = (e % 76) * 4;
                    const int byte = (s * XSTRIDE_B + c * 2) ^ ((s & 7) << 4);
                    s16x4 sv;
                    sv[0] = f2bf(ax[g].x); sv[1] = f2bf(ax[g].y);
                    sv[2] = f2bf(ax[g].z); sv[3] = f2bf(ax[g].w);
                    *reinterpret_cast<s16x4*>(lds + byte) = sv;
                }
            }
        }
        LDS_BARRIER();          // tile-m rows visible; later x loads stay in flight

#pragma unroll
        for (int kk = 0; kk < 10; ++kk) {
            const int row = m * 16 + lr;
            const int byte = (row * XSTRIDE_B + kk * 64 + lg * 16) ^ ((row & 7) << 4);
            const bf16x8 a = *reinterpret_cast<const bf16x8*>(lds + byte);
            acc[m] = __builtin_amdgcn_mfma_f32_16x16x32_bf16(
                wfrag[kk], a, acc[m], 0, 0, 0);
        }
    }

    // ---- write t (bf16, swizzled, 8B-packed) ----
    // swapped-operand D: col(lane&15)=s-in-tile, row(lg*4+r)=t-col-in-tile
#pragma unroll
    for (int st = 0; st < 5; ++st) {
        const int s = st * 16 + lr;
        const int c0 = wv * 16 + lg * 4;
        const int byte = (s * TSTRIDE_B + c0 * 2) ^ ((s & 7) << 4);
        s16x4 sv;
        sv[0] = f2bf(acc[st][0]); sv[1] = f2bf(acc[st][1]);
        sv[2] = f2bf(acc[st][2]); sv[3] = f2bf(acc[st][3]);
        *reinterpret_cast<s16x4*>(t_lds + byte) = sv;
    }
    LDS_BARRIER();

    // ---- phase 2: 15 upper-triangle G tiles in registers ----
    const int idx0 = wv;            // 0..7  (5 diagonal + 3 upper)
    const int idx1 = wv + 8;        // 8..14 (upper), wv==7 -> invalid
    const int ti0 = TI_LUT[idx0], tj0 = TJ_LUT[idx0];

    f32x4 g0 = (f32x4){0.f, 0.f, 0.f, 0.f};
#pragma unroll
    for (int kk = 0; kk < 4; ++kk) {
        const int ra = ti0 * 16 + lr;
        const int ba = (ra * TSTRIDE_B + kk * 64 + lg * 16) ^ ((ra & 7) << 4);
        const int rb = tj0 * 16 + lr;
        const int bb = (rb * TSTRIDE_B + kk * 64 + lg * 16) ^ ((rb & 7) << 4);
        g0 = __builtin_amdgcn_mfma_f32_16x16x32_bf16(
            *reinterpret_cast<const bf16x8*>(t_lds + ba),
            *reinterpret_cast<const bf16x8*>(t_lds + bb), g0, 0, 0, 0);
    }
    if (wv < 5) {                   // diagonal: extract norms
#pragma unroll
        for (int r = 0; r < 4; ++r)
            if (lr == lg * 4 + r) norms[wv * 16 + lr] = g0[r];
    }

    f32x4 g1 = (f32x4){0.f, 0.f, 0.f, 0.f};
    int ti1 = 0, tj1 = 0;
    if (idx1 < 15) {
        ti1 = TI_LUT[idx1]; tj1 = TJ_LUT[idx1];
#pragma unroll
        for (int kk = 0; kk < 4; ++kk) {
            const int ra = ti1 * 16 + lr;
            const int ba = (ra * TSTRIDE_B + kk * 64 + lg * 16) ^ ((ra & 7) << 4);
            const int rb = tj1 * 16 + lr;
            const int bb = (rb * TSTRIDE_B + kk * 64 + lg * 16) ^ ((rb & 7) << 4);
            g1 = __builtin_amdgcn_mfma_f32_16x16x32_bf16(
                *reinterpret_cast<const bf16x8*>(t_lds + ba),
                *reinterpret_cast<const bf16x8*>(t_lds + bb), g1, 0, 0, 0);
        }
    }
    LDS_BARRIER();                  // norms visible to all waves

    // ---- epilogue: out[i][j] = norms[i] + norms[j] - 2 G[i][j] (+mirror) ----
    float* __restrict__ ob = out + (size_t)batch * NS * NS;

    {   // tile idx0
        const int j = tj0 * 16 + lr;
        const float nj = norms[j];
        float v[4];
#pragma unroll
        for (int r = 0; r < 4; ++r) {
            const int i = ti0 * 16 + lg * 4 + r;
            v[r] = norms[i] + nj - 2.f * g0[r];
            if (i < NS && j < NS) ob[i * NS + j] = v[r];
        }
        if (ti0 != tj0 && j < NS) {             // upper tiles of idx0 = 5,6,7
            const int i0 = ti0 * 16 + lg * 4;   // i0+3 <= 19 < NS
            *reinterpret_cast<float2*>(ob + j * NS + i0)     = make_float2(v[0], v[1]);
            *reinterpret_cast<float2*>(ob + j * NS + i0 + 2) = make_float2(v[2], v[3]);
        }
    }
    if (idx1 < 15) {
        const int j = tj1 * 16 + lr;
        const float nj = norms[j];
        float v[4];
#pragma unroll
        for (int r = 0; r < 4; ++r) {
            const int i = ti1 * 16 + lg * 4 + r;
            v[r] = norms[i] + nj - 2.f * g1[r];
            if (i < NS && j < NS) ob[i * NS + j] = v[r];
        }
        if (j < NS) {                           // strict-upper: vectorized mirror
            const int i0 = ti1 * 16 + lg * 4;   // ti1 <= 3 -> i0+3 <= 63 < NS
            *reinterpret_cast<float2*>(ob + j * NS + i0)     = make_float2(v[0], v[1]);
            *reinterpret_cast<float2*>(ob + j * NS + i0 + 2) = make_float2(v[2], v[3]);
        }
    }
}

extern "C" void kernel_launch(void* const* d_in, const int* in_sizes, int n_in,
                              void* d_out, int out_size, void* d_ws, size_t ws_size,
                              hipStream_t stream) {
    const float* x = (const float*)d_in[0];   // (512, 66, 304) f32
    const float* W = (const float*)d_in[1];   // (128, 304) f32
    // d_in[2] = b : cancels in the pairwise difference, unused.
    float* out = (float*)d_out;               // (512, 66, 66) f32

    treeprobe_mfma<<<NBATCH, NTHREADS, 0, stream>>>(x, W, out);
}

// Round 8
// 20.434 us; speedup vs baseline: 1.7437x; 1.2543x over previous
//
#include <hip/hip_runtime.h>
#include <hip/hip_bf16.h>

#define NBATCH 512
#define NS 66
#define ND 304
#define NK 128
#define NTHREADS 512       // 8 waves
#define NBLOCKS (NBATCH / 2)   // persistent: 2 batches per block, 1 block/CU

#define XSTRIDE_B 640      // 320 bf16 per row (K padded 304->320)
#define XBYTES (80 * XSTRIDE_B)             // 51200
#define TSTRIDE_B 256      // 128 bf16 per row
#define TBYTES (80 * TSTRIDE_B)             // 20480

typedef __attribute__((ext_vector_type(8))) short bf16x8;
typedef __attribute__((ext_vector_type(4))) short s16x4;
typedef __attribute__((ext_vector_type(4))) float f32x4;

__device__ __forceinline__ short f2bf(float x) {
    return __builtin_bit_cast(short, __float2bfloat16(x));
}

// 15 upper-triangle 16x16 tiles of G: 5 diagonal first, then 10 strict-upper.
__device__ const int TI_LUT[15] = {0,1,2,3,4, 0,0,0,0,1,1,1,2,2,3};
__device__ const int TJ_LUT[15] = {0,1,2,3,4, 1,2,3,4,2,3,4,3,4,4};

// raw barrier: this wave's LDS ops done + all waves arrived.
// Does NOT drain vmcnt -> prefetch global loads stay in flight across it.
#define LDS_BARRIER() asm volatile("s_waitcnt lgkmcnt(0)\n\ts_barrier" ::: "memory")

__global__ __launch_bounds__(NTHREADS, 2) void treeprobe_mfma(
    const float* __restrict__ x,   // [512][66][304]
    const float* __restrict__ W,   // [128][304]
    float* __restrict__ out)       // [512][66][66]
{
    __shared__ __align__(16) char lds[XBYTES + TBYTES + 80 * 4];
    char* const t_lds = lds + XBYTES;
    float* const norms = (float*)(lds + XBYTES + TBYTES);

    const int tid  = threadIdx.x;
    const int lane = tid & 63;
    const int wv   = tid >> 6;      // wave 0..7 : N-tile (16 t-cols)
    const int lr   = lane & 15;
    const int lg   = lane >> 4;     // 0..3

    const int b0 = blockIdx.x * 2;
    const float* __restrict__ xb0 = x + (size_t)b0 * NS * ND;
    const float* __restrict__ xb1 = xb0 + NS * ND;

    // ---- 1) W loads FIRST (retire before x0 -> wfrag convert doesn't wait x) ----
    const int wc = wv * 16 + lr;                  // W row (t col) 0..127
    const float* __restrict__ wr = W + wc * ND;
    float4 wp[20];
#pragma unroll
    for (int kk = 0; kk < 10; ++kk) {
        const int k0 = kk * 32 + lg * 8;
        if (k0 < ND) {
            wp[kk * 2]     = *reinterpret_cast<const float4*>(wr + k0);
            wp[kk * 2 + 1] = *reinterpret_cast<const float4*>(wr + k0 + 4);
        } else {
            wp[kk * 2] = wp[kk * 2 + 1] = make_float4(0.f, 0.f, 0.f, 0.f);
        }
    }

    // ---- 2) x(b0) loads (5016 float4) ----
    float4 ax[10];
#pragma unroll
    for (int g = 0; g < 10; ++g) {
        const int e = g * NTHREADS + tid;
        ax[g] = (e < 5016)
            ? *reinterpret_cast<const float4*>(xb0 + (e / 76) * ND + (e % 76) * 4)
            : make_float4(0.f, 0.f, 0.f, 0.f);
    }

    // ---- 3) zero-fill pads ONCE (x rows 66..79; k-pad cols of rows 0..65;
    //         both persist: batch staging never touches them) ----
    for (int i = tid; i < 560; i += NTHREADS) {
        const int row = 66 + i / 40;
        *reinterpret_cast<f32x4*>(lds + row * XSTRIDE_B + (i % 40) * 16) =
            (f32x4){0.f, 0.f, 0.f, 0.f};
    }
    for (int i = tid; i < 132; i += NTHREADS) {
        const int row = i >> 1;
        const int byte = (row * XSTRIDE_B + 608 + (i & 1) * 16) ^ ((row & 7) << 4);
        *reinterpret_cast<f32x4*>(lds + byte) = (f32x4){0.f, 0.f, 0.f, 0.f};
    }

    // ---- 4) W -> A-operand fragments (waits W loads only) ----
    bf16x8 wfrag[10];
#pragma unroll
    for (int kk = 0; kk < 10; ++kk) {
        bf16x8 f;
        f[0] = f2bf(wp[kk * 2].x);     f[1] = f2bf(wp[kk * 2].y);
        f[2] = f2bf(wp[kk * 2].z);     f[3] = f2bf(wp[kk * 2].w);
        f[4] = f2bf(wp[kk * 2 + 1].x); f[5] = f2bf(wp[kk * 2 + 1].y);
        f[6] = f2bf(wp[kk * 2 + 1].z); f[7] = f2bf(wp[kk * 2 + 1].w);
        wfrag[kk] = f;
    }

    // ---- 5) x(b0) convert + LDS write (swizzled) ----
#pragma unroll
    for (int g = 0; g < 10; ++g) {
        const int e = g * NTHREADS + tid;
        if (e < 5016) {
            const int s = e / 76;
            const int c = (e % 76) * 4;
            const int byte = (s * XSTRIDE_B + c * 2) ^ ((s & 7) << 4);
            s16x4 sv;
            sv[0] = f2bf(ax[g].x); sv[1] = f2bf(ax[g].y);
            sv[2] = f2bf(ax[g].z); sv[3] = f2bf(ax[g].w);
            *reinterpret_cast<s16x4*>(lds + byte) = sv;
        }
    }

    // ---- 6) issue x(b1) prefetch into registers (streams under b0 compute) ----
    float4 ax2[10];
#pragma unroll
    for (int g = 0; g < 10; ++g) {
        const int e = g * NTHREADS + tid;
        ax2[g] = (e < 5016)
            ? *reinterpret_cast<const float4*>(xb1 + (e / 76) * ND + (e % 76) * 4)
            : make_float4(0.f, 0.f, 0.f, 0.f);
    }

    LDS_BARRIER();      // x(b0) staged; b1 loads remain in flight

    // ================== 2 batches, software-pipelined ==================
#pragma unroll
    for (int it = 0; it < 2; ++it) {
        // ---- phase 1: t = x . W^T (swapped operands) ----
        f32x4 acc[5];
#pragma unroll
        for (int st = 0; st < 5; ++st) acc[st] = (f32x4){0.f, 0.f, 0.f, 0.f};

#pragma unroll
        for (int kk = 0; kk < 10; ++kk) {
            bf16x8 a[5];
#pragma unroll
            for (int st = 0; st < 5; ++st) {
                const int row = st * 16 + lr;
                const int byte = (row * XSTRIDE_B + kk * 64 + lg * 16) ^ ((row & 7) << 4);
                a[st] = *reinterpret_cast<const bf16x8*>(lds + byte);
            }
#pragma unroll
            for (int st = 0; st < 5; ++st)
                acc[st] = __builtin_amdgcn_mfma_f32_16x16x32_bf16(
                    wfrag[kk], a[st], acc[st], 0, 0, 0);
        }

        // ---- write t (bf16, swizzled, 8B-packed) ----
        // D: col(lane&15)=s-in-tile, row(lg*4+r)=t-col-in-tile
#pragma unroll
        for (int st = 0; st < 5; ++st) {
            const int s = st * 16 + lr;
            const int c0 = wv * 16 + lg * 4;
            const int byte = (s * TSTRIDE_B + c0 * 2) ^ ((s & 7) << 4);
            s16x4 sv;
            sv[0] = f2bf(acc[st][0]); sv[1] = f2bf(acc[st][1]);
            sv[2] = f2bf(acc[st][2]); sv[3] = f2bf(acc[st][3]);
            *reinterpret_cast<s16x4*>(t_lds + byte) = sv;
        }
        LDS_BARRIER();   // t visible; ALL waves past phase-1 x-reads -> x-LDS is dead

        // ---- phase 2: 15 upper-triangle G tiles in registers ----
        const int idx0 = wv;            // 0..7  (5 diagonal + 3 upper)
        const int idx1 = wv + 8;        // 8..14 (upper), wv==7 -> invalid
        const int ti0 = TI_LUT[idx0], tj0 = TJ_LUT[idx0];

        f32x4 g0 = (f32x4){0.f, 0.f, 0.f, 0.f};
#pragma unroll
        for (int kk = 0; kk < 4; ++kk) {
            const int ra = ti0 * 16 + lr;
            const int ba = (ra * TSTRIDE_B + kk * 64 + lg * 16) ^ ((ra & 7) << 4);
            const int rb = tj0 * 16 + lr;
            const int bb = (rb * TSTRIDE_B + kk * 64 + lg * 16) ^ ((rb & 7) << 4);
            g0 = __builtin_amdgcn_mfma_f32_16x16x32_bf16(
                *reinterpret_cast<const bf16x8*>(t_lds + ba),
                *reinterpret_cast<const bf16x8*>(t_lds + bb), g0, 0, 0, 0);
        }
        if (wv < 5) {                   // diagonal: extract norms
#pragma unroll
            for (int r = 0; r < 4; ++r)
                if (lr == lg * 4 + r) norms[wv * 16 + lr] = g0[r];
        }

        f32x4 g1 = (f32x4){0.f, 0.f, 0.f, 0.f};
        int ti1 = 0, tj1 = 0;
        if (idx1 < 15) {
            ti1 = TI_LUT[idx1]; tj1 = TJ_LUT[idx1];
#pragma unroll
            for (int kk = 0; kk < 4; ++kk) {
                const int ra = ti1 * 16 + lr;
                const int ba = (ra * TSTRIDE_B + kk * 64 + lg * 16) ^ ((ra & 7) << 4);
                const int rb = tj1 * 16 + lr;
                const int bb = (rb * TSTRIDE_B + kk * 64 + lg * 16) ^ ((rb & 7) << 4);
                g1 = __builtin_amdgcn_mfma_f32_16x16x32_bf16(
                    *reinterpret_cast<const bf16x8*>(t_lds + ba),
                    *reinterpret_cast<const bf16x8*>(t_lds + bb), g1, 0, 0, 0);
            }
        }

        // ---- stage x(b1) into x-LDS (it==0 only): x-LDS dead, overlaps phase 2 ----
        if (it == 0) {
#pragma unroll
            for (int g = 0; g < 10; ++g) {
                const int e = g * NTHREADS + tid;
                if (e < 5016) {
                    const int s = e / 76;
                    const int c = (e % 76) * 4;
                    const int byte = (s * XSTRIDE_B + c * 2) ^ ((s & 7) << 4);
                    s16x4 sv;
                    sv[0] = f2bf(ax2[g].x); sv[1] = f2bf(ax2[g].y);
                    sv[2] = f2bf(ax2[g].z); sv[3] = f2bf(ax2[g].w);
                    *reinterpret_cast<s16x4*>(lds + byte) = sv;
                }
            }
        }
        LDS_BARRIER();   // norms (and, it==0, new x) visible

        // ---- epilogue: out[i][j] = norms[i] + norms[j] - 2 G[i][j] (+mirror) ----
        float* __restrict__ ob = out + (size_t)(b0 + it) * NS * NS;

        {   // tile idx0
            const int j = tj0 * 16 + lr;
            const float nj = norms[j];
            float v[4];
#pragma unroll
            for (int r = 0; r < 4; ++r) {
                const int i = ti0 * 16 + lg * 4 + r;
                v[r] = norms[i] + nj - 2.f * g0[r];
                if (i < NS && j < NS) ob[i * NS + j] = v[r];
            }
            if (ti0 != tj0 && j < NS) {             // upper tiles of idx0 = 5,6,7
                const int i0 = ti0 * 16 + lg * 4;   // i0+3 <= 15 < NS
                *reinterpret_cast<float2*>(ob + j * NS + i0)     = make_float2(v[0], v[1]);
                *reinterpret_cast<float2*>(ob + j * NS + i0 + 2) = make_float2(v[2], v[3]);
            }
        }
        if (idx1 < 15) {
            const int j = tj1 * 16 + lr;
            const float nj = norms[j];
            float v[4];
#pragma unroll
            for (int r = 0; r < 4; ++r) {
                const int i = ti1 * 16 + lg * 4 + r;
                v[r] = norms[i] + nj - 2.f * g1[r];
                if (i < NS && j < NS) ob[i * NS + j] = v[r];
            }
            if (j < NS) {                           // strict-upper: vectorized mirror
                const int i0 = ti1 * 16 + lg * 4;   // ti1 <= 3 -> i0+3 <= 63 < NS
                *reinterpret_cast<float2*>(ob + j * NS + i0)     = make_float2(v[0], v[1]);
                *reinterpret_cast<float2*>(ob + j * NS + i0 + 2) = make_float2(v[2], v[3]);
            }
        }
    }
}

extern "C" void kernel_launch(void* const* d_in, const int* in_sizes, int n_in,
                              void* d_out, int out_size, void* d_ws, size_t ws_size,
                              hipStream_t stream) {
    const float* x = (const float*)d_in[0];   // (512, 66, 304) f32
    const float* W = (const float*)d_in[1];   // (128, 304) f32
    // d_in[2] = b : cancels in the pairwise difference, unused.
    float* out = (float*)d_out;               // (512, 66, 66) f32

    treeprobe_mfma<<<NBLOCKS, NTHREADS, 0, stream>>>(x, W, out);
}